// Round 1
// baseline (16194.966 us; speedup 1.0000x reference)
//
#include <hip/hip_runtime.h>
#include <hip/hip_bf16.h>

#define TPB   512
#define WROWS 64
#define CDIM  192
#define HEADS 6
#define HD    32
#define SXLD  196   // f32 leading dim for staging / x buffer (196%32=4 words -> spread banks)
#define SQLD  194   // f32 leading dim for q (194%32=2)
#define SKLD  194   // bf16 leading dim for k/v
#define EPSF  1e-12f
#define SCALE 0.07216878364870323f  // 1/sqrt(192)

__device__ __forceinline__ float dot4(float4 a, float4 b) {
  return a.x * b.x + a.y * b.y + a.z * b.z + a.w * b.w;
}

__global__ __launch_bounds__(TPB) void wa_fused(
    const float* __restrict__ qx, const float* __restrict__ kvx,
    const float* __restrict__ pos,
    const float* __restrict__ Wq, const float* __restrict__ bq,
    const float* __restrict__ Wkv, const float* __restrict__ bkv,
    const float* __restrict__ Wp, const float* __restrict__ bp,
    float* __restrict__ out, int BKV)
{
  __shared__ __align__(16) float sX[WROWS * SXLD];           // staging (qx+pos, then kvx), then attn output x
  __shared__ __align__(16) float sQ[WROWS * SQLD];           // q (f32)
  __shared__ __align__(16) __hip_bfloat16 sK[WROWS * SKLD];  // k (bf16)
  __shared__ __align__(16) __hip_bfloat16 sV[WROWS * SKLD];  // v (bf16)
  __shared__ float qinv[WROWS * HEADS];
  __shared__ float kinv[WROWS * HEADS];

  const int tid = threadIdx.x;
  const int b = blockIdx.x;
  const size_t qoff = (size_t)b * (WROWS * CDIM);
  const int kvb = b % BKV;
  const size_t kvoff = (size_t)kvb * (WROWS * CDIM);

  // ---- stage qx + pos (f32, float4) ----
  {
    const float4* g = (const float4*)(qx + qoff);
    const float4* p4 = (const float4*)pos;
    for (int e = tid; e < WROWS * CDIM / 4; e += TPB) {
      int row = e / (CDIM / 4), c4 = e % (CDIM / 4);
      float4 a = g[e];
      float4 p = p4[e];
      a.x += p.x; a.y += p.y; a.z += p.z; a.w += p.w;
      ((float4*)sX)[row * (SXLD / 4) + c4] = a;
    }
  }
  __syncthreads();

  // ---- q projection: q = sX @ Wq^T + bq  -> sQ (f32) ----
  {
    const int ti = tid >> 5;   // 0..15
    const int tj = tid & 31;   // 0..31
    float acc[4][6];
    #pragma unroll
    for (int jj = 0; jj < 6; ++jj) {
      float bv = bq[tj + 32 * jj];
      #pragma unroll
      for (int a = 0; a < 4; ++a) acc[a][jj] = bv;
    }
    const float4* W4 = (const float4*)Wq;
    for (int c4 = 0; c4 < CDIM / 4; ++c4) {
      float4 w[6];
      #pragma unroll
      for (int jj = 0; jj < 6; ++jj) w[jj] = W4[(tj + 32 * jj) * 48 + c4];
      #pragma unroll
      for (int a = 0; a < 4; ++a) {
        float4 x4 = ((const float4*)sX)[(ti + 16 * a) * (SXLD / 4) + c4];
        #pragma unroll
        for (int jj = 0; jj < 6; ++jj) acc[a][jj] += dot4(x4, w[jj]);
      }
    }
    #pragma unroll
    for (int a = 0; a < 4; ++a)
      #pragma unroll
      for (int jj = 0; jj < 6; ++jj)
        sQ[(ti + 16 * a) * SQLD + tj + 32 * jj] = acc[a][jj];
  }
  __syncthreads();

  // ---- stage kvx (overwrite sX) ----
  {
    const float4* g = (const float4*)(kvx + kvoff);
    for (int e = tid; e < WROWS * CDIM / 4; e += TPB) {
      int row = e / (CDIM / 4), c4 = e % (CDIM / 4);
      ((float4*)sX)[row * (SXLD / 4) + c4] = g[e];
    }
  }
  __syncthreads();

  // ---- kv projection: kv = sX @ Wkv^T + bkv -> sK, sV (bf16) ----
  {
    const int ti = tid >> 5;
    const int tj = tid & 31;
    float acc[4][12];
    #pragma unroll
    for (int jj = 0; jj < 12; ++jj) {
      float bv = bkv[tj + 32 * jj];
      #pragma unroll
      for (int a = 0; a < 4; ++a) acc[a][jj] = bv;
    }
    const float4* W4 = (const float4*)Wkv;
    for (int c4 = 0; c4 < CDIM / 4; ++c4) {
      float4 w[12];
      #pragma unroll
      for (int jj = 0; jj < 12; ++jj) w[jj] = W4[(tj + 32 * jj) * 48 + c4];
      #pragma unroll
      for (int a = 0; a < 4; ++a) {
        float4 x4 = ((const float4*)sX)[(ti + 16 * a) * (SXLD / 4) + c4];
        #pragma unroll
        for (int jj = 0; jj < 12; ++jj) acc[a][jj] += dot4(x4, w[jj]);
      }
    }
    #pragma unroll
    for (int a = 0; a < 4; ++a) {
      #pragma unroll
      for (int jj = 0; jj < 12; ++jj) {
        int col = tj + 32 * jj;
        int row = ti + 16 * a;
        float v = acc[a][jj];
        if (col < CDIM) sK[row * SKLD + col] = __float2bfloat16(v);
        else            sV[row * SKLD + (col - CDIM)] = __float2bfloat16(v);
      }
    }
  }
  __syncthreads();

  // ---- per (row, head) l2-norm inverses ----
  if (tid < WROWS * HEADS) {
    const int r = tid / HEADS, h = tid % HEADS;
    const int qb = r * SQLD + h * HD;
    const int kb = r * SKLD + h * HD;
    float sq = 0.f, sk = 0.f;
    #pragma unroll
    for (int d = 0; d < HD; ++d) {
      float qv = sQ[qb + d];
      sq += qv * qv;
      float kv = __bfloat162float(sK[kb + d]);
      sk += kv * kv;
    }
    qinv[tid] = 1.0f / fmaxf(sqrtf(sq), EPSF);
    kinv[tid] = 1.0f / fmaxf(sqrtf(sk), EPSF);
  }
  __syncthreads();

  // ---- attention (per head); x -> sX (f32) ----
  {
    const int r = tid >> 3;    // 0..63 (q row)
    const int oct = tid & 7;   // 8 lanes per row
    for (int h = 0; h < HEADS; ++h) {
      float qreg[HD];
      const int qb = r * SQLD + h * HD;
      #pragma unroll
      for (int d = 0; d < HD; ++d) qreg[d] = sQ[qb + d];
      const float qi = qinv[r * HEADS + h] * SCALE;

      float s[8];
      #pragma unroll
      for (int kk0 = 0; kk0 < 8; ++kk0) {
        const int kk = oct * 8 + kk0;
        const __hip_bfloat16* krow = sK + kk * SKLD + h * HD;
        float a = 0.f;
        #pragma unroll
        for (int d = 0; d < HD; ++d) a += qreg[d] * __bfloat162float(krow[d]);
        s[kk0] = a * qi * kinv[kk * HEADS + h];
      }
      // softmax over 64 (8 regs x 8 lanes)
      float m = s[0];
      #pragma unroll
      for (int kk0 = 1; kk0 < 8; ++kk0) m = fmaxf(m, s[kk0]);
      m = fmaxf(m, __shfl_xor(m, 1));
      m = fmaxf(m, __shfl_xor(m, 2));
      m = fmaxf(m, __shfl_xor(m, 4));
      float sum = 0.f;
      #pragma unroll
      for (int kk0 = 0; kk0 < 8; ++kk0) { s[kk0] = __expf(s[kk0] - m); sum += s[kk0]; }
      sum += __shfl_xor(sum, 1);
      sum += __shfl_xor(sum, 2);
      sum += __shfl_xor(sum, 4);
      const float inv = 1.0f / sum;
      #pragma unroll
      for (int kk0 = 0; kk0 < 8; ++kk0) s[kk0] *= inv;

      // x[r][h*32+d] = sum_k attn * v
      #pragma unroll
      for (int d = 0; d < HD; ++d) {
        float a = 0.f;
        #pragma unroll
        for (int kk0 = 0; kk0 < 8; ++kk0)
          a += s[kk0] * __bfloat162float(sV[(oct * 8 + kk0) * SKLD + h * HD + d]);
        a += __shfl_xor(a, 1);
        a += __shfl_xor(a, 2);
        a += __shfl_xor(a, 4);
        if ((d >> 2) == oct) sX[r * SXLD + h * HD + d] = a;
      }
    }
  }
  __syncthreads();

  // ---- out projection: out = x @ Wp^T + bp ----
  {
    const int i = tid >> 3;    // 0..63
    const int oct = tid & 7;   // 24 cols each
    float acc[24];
    #pragma unroll
    for (int jj = 0; jj < 24; ++jj) acc[jj] = bp[oct * 24 + jj];
    const float4* W4 = (const float4*)Wp;
    const float4* x4p = (const float4*)sX + i * (SXLD / 4);
    for (int c4 = 0; c4 < CDIM / 4; ++c4) {
      float4 x4 = x4p[c4];
      #pragma unroll
      for (int jj = 0; jj < 24; ++jj)
        acc[jj] += dot4(x4, W4[(oct * 24 + jj) * 48 + c4]);
    }
    float4* o4 = (float4*)(out + qoff + i * CDIM + oct * 24);
    #pragma unroll
    for (int q4 = 0; q4 < 6; ++q4)
      o4[q4] = make_float4(acc[4 * q4], acc[4 * q4 + 1], acc[4 * q4 + 2], acc[4 * q4 + 3]);
  }
}

extern "C" void kernel_launch(void* const* d_in, const int* in_sizes, int n_in,
                              void* d_out, int out_size, void* d_ws, size_t ws_size,
                              hipStream_t stream) {
  const float* qx  = (const float*)d_in[0];
  const float* kvx = (const float*)d_in[1];
  const float* pos = (const float*)d_in[2];
  const float* Wq  = (const float*)d_in[3];
  const float* bq  = (const float*)d_in[4];
  const float* Wkv = (const float*)d_in[5];
  const float* bkv = (const float*)d_in[6];
  const float* Wp  = (const float*)d_in[7];
  const float* bp  = (const float*)d_in[8];
  float* out = (float*)d_out;

  const int BQ  = in_sizes[0] / (WROWS * CDIM);
  const int BKV = in_sizes[1] / (WROWS * CDIM);

  wa_fused<<<BQ, TPB, 0, stream>>>(qx, kvx, pos, Wq, bq, Wkv, bkv, Wp, bp, out, BKV);
}

// Round 2
// 964.036 us; speedup vs baseline: 16.7991x; 16.7991x over previous
//
#include <hip/hip_runtime.h>

#define TPB   512
#define CDIM  192
#define HEADS 6
#define HD    32
#define LDX   200   // bf16 leading dim for 64xCDIM row-major MFMA buffers
#define LDSS  68    // f32 leading dim for S
#define LDP   72    // bf16 leading dim for P
#define LDV   72    // bf16 leading dim for Vt (rows = v-cols, 64 valid entries)
#define SCALE 0.07216878364870323f  // 1/sqrt(192)
#define EPSF  1e-12f

using short8 = __attribute__((ext_vector_type(8))) short;
using f32x4  = __attribute__((ext_vector_type(4))) float;
using us4    = __attribute__((ext_vector_type(4))) unsigned short;

__device__ __forceinline__ unsigned short f2b(float f) {
  union { float f; unsigned u; } a; a.f = f;
  unsigned u = a.u;
  u += 0x7fffu + ((u >> 16) & 1u);   // round-to-nearest-even
  return (unsigned short)(u >> 16);
}
__device__ __forceinline__ float b2f(unsigned short h) {
  union { unsigned u; float f; } a; a.u = ((unsigned)h) << 16;
  return a.f;
}
#define MFMA(a, b, c) __builtin_amdgcn_mfma_f32_16x16x32_bf16((a), (b), (c), 0, 0, 0)

// ---- pre-kernel: cast weights f32 -> bf16 into workspace ----
#define NWQ  36864   // 192*192
#define NWKV 73728   // 384*192
#define NWP  36864
__global__ void cvt_weights(const float* __restrict__ Wq, const float* __restrict__ Wkv,
                            const float* __restrict__ Wp, unsigned short* __restrict__ o) {
  int i = blockIdx.x * blockDim.x + threadIdx.x;
  if (i < NWQ) o[i] = f2b(Wq[i]);
  else if (i < NWQ + NWKV) o[i] = f2b(Wkv[i - NWQ]);
  else if (i < NWQ + NWKV + NWP) o[i] = f2b(Wp[i - NWQ - NWKV]);
}

__global__ __launch_bounds__(TPB, 1) void wa_mfma(
    const float* __restrict__ qx, const float* __restrict__ kvx,
    const float* __restrict__ pos,
    const float* __restrict__ bq, const float* __restrict__ bkv,
    const float* __restrict__ bp,
    const unsigned short* __restrict__ Wqb, const unsigned short* __restrict__ Wkvb,
    const unsigned short* __restrict__ Wpb,
    float* __restrict__ out, int BKV)
{
  __shared__ __align__(16) unsigned short sXb[64 * LDX];   // qx staging; later S (f32) lives here
  __shared__ __align__(16) unsigned short sQb[64 * LDX];   // q (bf16, un-normalized)
  __shared__ __align__(16) unsigned short sKb[64 * LDX];   // k (bf16)
  __shared__ __align__(16) unsigned short sVt[CDIM * LDV]; // v transposed: sVt[vcol][kvrow]
  __shared__ __align__(16) unsigned short sXo[64 * LDX];   // kvx staging; later attention output x
  __shared__ __align__(16) unsigned short sP[64 * LDP];    // softmax probs (bf16)
  __shared__ __align__(16) float qinvA[HEADS * 64];
  __shared__ __align__(16) float kinvA[HEADS * 64];

  float* sS = reinterpret_cast<float*>(sXb);               // 64*LDSS*4 = 17408 B <= 25600 B

  const int tid  = threadIdx.x;
  const int wid  = tid >> 6;
  const int lane = tid & 63;
  const int l15  = lane & 15;
  const int l4   = lane >> 4;
  const int b    = blockIdx.x;
  const size_t qoff  = (size_t)b * (64 * CDIM);
  const size_t kvoff = (size_t)(b % BKV) * (64 * CDIM);

  // ================= Phase 1: prefetch kvx to regs; stage qx+pos -> sXb (bf16) =================
  float4 kreg[6];
  {
    const float4* gk = (const float4*)(kvx + kvoff);
    #pragma unroll
    for (int t = 0; t < 6; ++t) kreg[t] = gk[tid + t * TPB];

    const float4* gq = (const float4*)(qx + qoff);
    const float4* p4 = (const float4*)pos;
    #pragma unroll
    for (int t = 0; t < 6; ++t) {
      int e = tid + t * TPB, row = e / 48, c4 = e % 48;
      float4 a = gq[e], p = p4[e];
      us4 w; w.x = f2b(a.x + p.x); w.y = f2b(a.y + p.y); w.z = f2b(a.z + p.z); w.w = f2b(a.w + p.w);
      *(us4*)&sXb[row * LDX + c4 * 4] = w;
    }
  }
  __syncthreads();

  // ================= Phase 2: write kv staging (sXo); q projection (MFMA) =================
  {
    #pragma unroll
    for (int t = 0; t < 6; ++t) {
      int e = tid + t * TPB, row = e / 48, c4 = e % 48;
      float4 a = kreg[t];
      us4 w; w.x = f2b(a.x); w.y = f2b(a.y); w.z = f2b(a.z); w.w = f2b(a.w);
      *(us4*)&sXo[row * LDX + c4 * 4] = w;
    }
  }
  {
    const int mg = (wid & 1) * 2;       // m-tiles mg, mg+1
    const int ng = (wid >> 1) * 3;      // n-tiles ng..ng+2
    f32x4 acc[2][3];
    #pragma unroll
    for (int nn = 0; nn < 3; ++nn) {
      float bv = bq[(ng + nn) * 16 + l15];
      acc[0][nn] = f32x4{bv, bv, bv, bv};
      acc[1][nn] = f32x4{bv, bv, bv, bv};
    }
    for (int ks = 0; ks < 6; ++ks) {
      short8 a0 = *(const short8*)&sXb[(l15 + 16 * mg) * LDX + ks * 32 + l4 * 8];
      short8 a1 = *(const short8*)&sXb[(l15 + 16 * mg + 16) * LDX + ks * 32 + l4 * 8];
      #pragma unroll
      for (int nn = 0; nn < 3; ++nn) {
        short8 bb = *(const short8*)&Wqb[((ng + nn) * 16 + l15) * CDIM + ks * 32 + l4 * 8];
        acc[0][nn] = MFMA(a0, bb, acc[0][nn]);
        acc[1][nn] = MFMA(a1, bb, acc[1][nn]);
      }
    }
    #pragma unroll
    for (int mm = 0; mm < 2; ++mm)
      #pragma unroll
      for (int nn = 0; nn < 3; ++nn)
        #pragma unroll
        for (int r = 0; r < 4; ++r)
          sQb[(16 * (mg + mm) + l4 * 4 + r) * LDX + (ng + nn) * 16 + l15] = f2b(acc[mm][nn][r]);
  }
  __syncthreads();

  // ================= Phase 3: kv projection (MFMA); k -> sKb, v -> sVt (transposed) =================
  {
    const int mg = (wid & 1) * 2;
    const int ng = (wid >> 1) * 6;      // n-tiles ng..ng+5 (of 24)
    f32x4 acc[2][6];
    #pragma unroll
    for (int nn = 0; nn < 6; ++nn) {
      float bv = bkv[(ng + nn) * 16 + l15];
      acc[0][nn] = f32x4{bv, bv, bv, bv};
      acc[1][nn] = f32x4{bv, bv, bv, bv};
    }
    for (int ks = 0; ks < 6; ++ks) {
      short8 a0 = *(const short8*)&sXo[(l15 + 16 * mg) * LDX + ks * 32 + l4 * 8];
      short8 a1 = *(const short8*)&sXo[(l15 + 16 * mg + 16) * LDX + ks * 32 + l4 * 8];
      #pragma unroll
      for (int nn = 0; nn < 6; ++nn) {
        short8 bb = *(const short8*)&Wkvb[((ng + nn) * 16 + l15) * CDIM + ks * 32 + l4 * 8];
        acc[0][nn] = MFMA(a0, bb, acc[0][nn]);
        acc[1][nn] = MFMA(a1, bb, acc[1][nn]);
      }
    }
    #pragma unroll
    for (int mm = 0; mm < 2; ++mm)
      #pragma unroll
      for (int nn = 0; nn < 6; ++nn) {
        int colg = (ng + nn) * 16 + l15;
        #pragma unroll
        for (int r = 0; r < 4; ++r) {
          int row = 16 * (mg + mm) + l4 * 4 + r;
          unsigned short hv = f2b(acc[mm][nn][r]);
          if (colg < CDIM) sKb[row * LDX + colg] = hv;
          else             sVt[(colg - CDIM) * LDV + row] = hv;
        }
      }
  }
  __syncthreads();

  // ================= Phase 4: l2-norm inverses from bf16 q/k =================
  if (tid < HEADS * 64) {
    int h = tid >> 6, r = tid & 63;
    int base = r * LDX + h * HD;
    float sq = 0.f, sk = 0.f;
    #pragma unroll
    for (int g = 0; g < 4; ++g) {
      short8 vq = *(const short8*)&sQb[base + g * 8];
      short8 vk = *(const short8*)&sKb[base + g * 8];
      #pragma unroll
      for (int j = 0; j < 8; ++j) {
        float fq = b2f((unsigned short)vq[j]); sq += fq * fq;
        float fk = b2f((unsigned short)vk[j]); sk += fk * fk;
      }
    }
    qinvA[tid] = 1.0f / fmaxf(sqrtf(sq), EPSF);
    kinvA[tid] = 1.0f / fmaxf(sqrtf(sk), EPSF);
  }
  __syncthreads();

  // ================= Phase 5: attention, pipelined {QK(h+1) || PV(h)} =================
  auto QK = [&](int h) {
    const int m = wid >> 1;
    const int nb = (wid & 1) * 2;
    short8 aq = *(const short8*)&sQb[(l15 + 16 * m) * LDX + h * HD + l4 * 8];
    #pragma unroll
    for (int t = 0; t < 2; ++t) {
      int n = nb + t;
      short8 bk = *(const short8*)&sKb[(l15 + 16 * n) * LDX + h * HD + l4 * 8];
      f32x4 c = f32x4{0.f, 0.f, 0.f, 0.f};
      c = MFMA(aq, bk, c);
      #pragma unroll
      for (int r = 0; r < 4; ++r)
        sS[(16 * m + l4 * 4 + r) * LDSS + 16 * n + l15] = c[r];
    }
  };
  auto SM = [&](int h) {
    const int r = tid >> 3, oct = tid & 7;
    float qs = qinvA[h * 64 + r] * SCALE;
    float4 k0 = *(const float4*)&kinvA[h * 64 + oct * 8];
    float4 k1 = *(const float4*)&kinvA[h * 64 + oct * 8 + 4];
    float4 s0 = *(const float4*)&sS[r * LDSS + oct * 8];
    float4 s1 = *(const float4*)&sS[r * LDSS + oct * 8 + 4];
    float v[8] = { s0.x * k0.x, s0.y * k0.y, s0.z * k0.z, s0.w * k0.w,
                   s1.x * k1.x, s1.y * k1.y, s1.z * k1.z, s1.w * k1.w };
    #pragma unroll
    for (int j = 0; j < 8; ++j) v[j] *= qs;
    float m8 = v[0];
    #pragma unroll
    for (int j = 1; j < 8; ++j) m8 = fmaxf(m8, v[j]);
    m8 = fmaxf(m8, __shfl_xor(m8, 1));
    m8 = fmaxf(m8, __shfl_xor(m8, 2));
    m8 = fmaxf(m8, __shfl_xor(m8, 4));
    float sum = 0.f;
    #pragma unroll
    for (int j = 0; j < 8; ++j) { v[j] = __expf(v[j] - m8); sum += v[j]; }
    sum += __shfl_xor(sum, 1);
    sum += __shfl_xor(sum, 2);
    sum += __shfl_xor(sum, 4);
    float inv = 1.0f / sum;
    us4 p0, p1;
    p0.x = f2b(v[0] * inv); p0.y = f2b(v[1] * inv); p0.z = f2b(v[2] * inv); p0.w = f2b(v[3] * inv);
    p1.x = f2b(v[4] * inv); p1.y = f2b(v[5] * inv); p1.z = f2b(v[6] * inv); p1.w = f2b(v[7] * inv);
    *(us4*)&sP[r * LDP + oct * 8] = p0;
    *(us4*)&sP[r * LDP + oct * 8 + 4] = p1;
  };
  auto PV = [&](int h) {
    const int m = wid >> 1, n = wid & 1;
    f32x4 c = f32x4{0.f, 0.f, 0.f, 0.f};
    #pragma unroll
    for (int ks = 0; ks < 2; ++ks) {
      short8 a = *(const short8*)&sP[(l15 + 16 * m) * LDP + ks * 32 + l4 * 8];
      short8 bb = *(const short8*)&sVt[(h * HD + 16 * n + l15) * LDV + ks * 32 + l4 * 8];
      c = MFMA(a, bb, c);
    }
    #pragma unroll
    for (int r = 0; r < 4; ++r)
      sXo[(16 * m + l4 * 4 + r) * LDX + h * HD + 16 * n + l15] = f2b(c[r]);
  };

  QK(0);
  __syncthreads();
  #pragma unroll
  for (int h = 0; h < HEADS; ++h) {
    SM(h);
    __syncthreads();
    if (h < HEADS - 1) QK(h + 1);
    PV(h);
    __syncthreads();
  }

  // ================= Phase 6: out projection (MFMA), f32 global stores =================
  {
    const int mg = (wid & 1) * 2;
    const int ng = (wid >> 1) * 3;
    f32x4 acc[2][3];
    #pragma unroll
    for (int nn = 0; nn < 3; ++nn) {
      float bv = bp[(ng + nn) * 16 + l15];
      acc[0][nn] = f32x4{bv, bv, bv, bv};
      acc[1][nn] = f32x4{bv, bv, bv, bv};
    }
    for (int ks = 0; ks < 6; ++ks) {
      short8 a0 = *(const short8*)&sXo[(l15 + 16 * mg) * LDX + ks * 32 + l4 * 8];
      short8 a1 = *(const short8*)&sXo[(l15 + 16 * mg + 16) * LDX + ks * 32 + l4 * 8];
      #pragma unroll
      for (int nn = 0; nn < 3; ++nn) {
        short8 bb = *(const short8*)&Wpb[((ng + nn) * 16 + l15) * CDIM + ks * 32 + l4 * 8];
        acc[0][nn] = MFMA(a0, bb, acc[0][nn]);
        acc[1][nn] = MFMA(a1, bb, acc[1][nn]);
      }
    }
    #pragma unroll
    for (int mm = 0; mm < 2; ++mm)
      #pragma unroll
      for (int nn = 0; nn < 3; ++nn)
        #pragma unroll
        for (int r = 0; r < 4; ++r) {
          int row = 16 * (mg + mm) + l4 * 4 + r;
          int col = (ng + nn) * 16 + l15;
          out[qoff + row * CDIM + col] = acc[mm][nn][r];
        }
  }
}

extern "C" void kernel_launch(void* const* d_in, const int* in_sizes, int n_in,
                              void* d_out, int out_size, void* d_ws, size_t ws_size,
                              hipStream_t stream) {
  const float* qx  = (const float*)d_in[0];
  const float* kvx = (const float*)d_in[1];
  const float* pos = (const float*)d_in[2];
  const float* Wq  = (const float*)d_in[3];
  const float* bq  = (const float*)d_in[4];
  const float* Wkv = (const float*)d_in[5];
  const float* bkv = (const float*)d_in[6];
  const float* Wp  = (const float*)d_in[7];
  const float* bp  = (const float*)d_in[8];
  float* out = (float*)d_out;
  unsigned short* wsb = (unsigned short*)d_ws;

  const int BQ  = in_sizes[0] / (64 * CDIM);
  const int BKV = in_sizes[1] / (64 * CDIM);

  const int ncvt = NWQ + NWKV + NWP;
  cvt_weights<<<(ncvt + 255) / 256, 256, 0, stream>>>(Wq, Wkv, Wp, wsb);

  wa_mfma<<<BQ, TPB, 0, stream>>>(qx, kvx, pos, bq, bkv, bp,
                                  wsb, wsb + NWQ, wsb + NWQ + NWKV, out, BKV);
}